// Round 13
// baseline (537.388 us; speedup 1.0000x reference)
//
#include <hip/hip_runtime.h>
#include <hip/hip_bf16.h>
#include <math.h>

#define NB 4
#define NN 2048
#define IND 256
#define TOT 256
#define NH 4
#define TI 16
#define TJ 32
#define M0V 4.0f   // fixed softmax shift; e = leaky(src+tgt) provably < 4

// ---------------- K1: proj = nodes @ W + b   (4 rows per block)
__global__ __launch_bounds__(256) void proj_kernel(
    const float* __restrict__ nodes, const float* __restrict__ Wp,
    const float* __restrict__ bp, float* __restrict__ proj) {
  __shared__ float nrow[4][IND];
  const int t = threadIdx.x;
  const int r0 = blockIdx.x * 4;
#pragma unroll
  for (int r = 0; r < 4; ++r) nrow[r][t] = nodes[(r0 + r) * IND + t];
  __syncthreads();
  float a0, a1, a2, a3;
  a0 = a1 = a2 = a3 = bp[t];
  for (int k = 0; k < IND; ++k) {
    const float w = Wp[k * TOT + t];
    a0 = fmaf(nrow[0][k], w, a0);
    a1 = fmaf(nrow[1][k], w, a1);
    a2 = fmaf(nrow[2][k], w, a2);
    a3 = fmaf(nrow[3][k], w, a3);
  }
  proj[(r0 + 0) * TOT + t] = a0;
  proj[(r0 + 1) * TOT + t] = a1;
  proj[(r0 + 2) * TOT + t] = a2;
  proj[(r0 + 3) * TOT + t] = a3;
}

// ---------------- K2: src/tgt = proj @ a_{src,tgt}   (1 wave per node, LDS tree)
__global__ __launch_bounds__(64) void srctgt_kernel(
    const float* __restrict__ proj, const float* __restrict__ asrc,
    const float* __restrict__ atgt, float* __restrict__ srcO,
    float* __restrict__ tgtO) {
  __shared__ float sred[64];
  const int t = threadIdx.x;
  const int n = blockIdx.x;
  float p[8] = {0.f, 0.f, 0.f, 0.f, 0.f, 0.f, 0.f, 0.f};
#pragma unroll
  for (int c = 0; c < 4; ++c) {
    const int col = t + 64 * c;
    const float v = proj[n * TOT + col];
    const float4 as = ((const float4*)asrc)[col];
    const float4 at = ((const float4*)atgt)[col];
    p[0] = fmaf(v, as.x, p[0]);
    p[1] = fmaf(v, as.y, p[1]);
    p[2] = fmaf(v, as.z, p[2]);
    p[3] = fmaf(v, as.w, p[3]);
    p[4] = fmaf(v, at.x, p[4]);
    p[5] = fmaf(v, at.y, p[5]);
    p[6] = fmaf(v, at.z, p[6]);
    p[7] = fmaf(v, at.w, p[7]);
  }
#pragma unroll
  for (int v = 0; v < 8; ++v) {
    sred[t] = p[v];
    __syncthreads();
    for (int s = 32; s > 0; s >>= 1) {
      if (t < s) sred[t] += sred[t + s];
      __syncthreads();
    }
    if (t == 0) {
      if (v < 4) srcO[n * NH + v] = sred[0];
      else       tgtO[n * NH + (v - 4)] = sred[0];
    }
    __syncthreads();
  }
}

// ---------------- K3: fused unnormalized softmax-agg, single barrier per j-tile
// Block = (b, 16-row i-tile), 256 threads. ia=t&15, ha=(t>>4)&3, jb=h=t>>6.
// acc_u[i] = sum_j e_u(i,j) z[j];  L = sum_j e_u;  out = acc_u / L.
__global__ __launch_bounds__(256) void agg_kernel(
    const int* __restrict__ adj, const float* __restrict__ proj,
    const float* __restrict__ srcI, const float* __restrict__ tgtI,
    float* __restrict__ out) {
  __shared__ float4 tgt_lds[NN];             // 32 KB
  __shared__ unsigned int bm_lds[TI * 66];   // 4.2 KB
  __shared__ float alpha_lds[2][TJ * 64];    // 16 KB double buffer (unnormalized e)
  __shared__ float Lred[4][NH][TI];          // [jb][ha][ia]
  __shared__ float rl_lds[TI][NH];
  const int t = threadIdx.x;
  const int b = blockIdx.x >> 7;
  const int i0 = (blockIdx.x & 127) << 4;
  const int* __restrict__ adjB = adj + (b * NN + i0) * NN;

#pragma unroll
  for (int c = 0; c < 8; ++c) {
    const int j = t + 256 * c;
    tgt_lds[j] = ((const float4*)tgtI)[b * NN + j];
  }
  // stage adjacency bitmask: wave wv packs rows 4wv..4wv+3, coalesced + ballot
  const int wv = t >> 6, lane = t & 63;
#pragma unroll
  for (int r8 = 0; r8 < 4; ++r8) {
    const int r = wv * 4 + r8;
    const int* __restrict__ arowS = adjB + r * NN;
#pragma unroll 4
    for (int c = 0; c < 32; ++c) {
      const unsigned long long m = __ballot(arowS[c * 64 + lane] > 0);
      if (lane == 0)
        *(unsigned long long*)&bm_lds[r * 66 + c * 2] = m;
    }
  }
  __syncthreads();

  const int ia = t & 15, ha = (t >> 4) & 3, jb = t >> 6;
  const int h = jb;                        // wave == head; t = h*64 + d
  const float svv = srcI[(b * NN + i0 + ia) * NH + ha];
  const float* __restrict__ zB = proj + (long)(b * NN) * TOT;
  float acc[TI];
#pragma unroll
  for (int i = 0; i < TI; ++i) acc[i] = 0.f;
  float Lp = 0.f;

  // prologue: stage jt=0 into buffer 0
  {
    const unsigned int word = bm_lds[ia * 66];
#pragma unroll
    for (int s = 0; s < 8; ++s) {
      const int jl = jb + s * 4;
      const float tv = ((const float*)&tgt_lds[jl])[ha];
      float e0 = svv + tv;
      e0 = e0 >= 0.f ? e0 : 0.2f * e0;
      const float v = ((word >> jl) & 1) ? __expf(e0 - M0V) : 0.f;
      alpha_lds[0][jl * 64 + ha * 16 + ia] = v;
      Lp += v;
    }
  }
  __syncthreads();

  for (int jt = 0; jt < NN / TJ; ++jt) {
    const int cur = jt & 1;
    // prefetch this tile's z into registers (static indices only)
    float zr[TJ];
#pragma unroll
    for (int jl = 0; jl < TJ; ++jl) zr[jl] = zB[(jt * TJ + jl) * TOT + t];
    // stage next tile into the other buffer (hides z latency under this VALU)
    if (jt < NN / TJ - 1) {
      const unsigned int word = bm_lds[ia * 66 + jt + 1];
#pragma unroll
      for (int s = 0; s < 8; ++s) {
        const int jl = jb + s * 4;
        const int jj = (jt + 1) * TJ + jl;
        const float tv = ((const float*)&tgt_lds[jj])[ha];
        float e0 = svv + tv;
        e0 = e0 >= 0.f ? e0 : 0.2f * e0;
        const float v = ((word >> jl) & 1) ? __expf(e0 - M0V) : 0.f;
        alpha_lds[cur ^ 1][jl * 64 + ha * 16 + ia] = v;
        Lp += v;
      }
    }
    // PV on current buffer (broadcast LDS reads, registers z)
#pragma unroll
    for (int jl = 0; jl < TJ; ++jl) {
      const float4* __restrict__ ap = (const float4*)&alpha_lds[cur][jl * 64 + h * 16];
      const float4 q0 = ap[0], q1 = ap[1], q2 = ap[2], q3 = ap[3];
      const float zv = zr[jl];
      acc[0]  = fmaf(q0.x, zv, acc[0]);
      acc[1]  = fmaf(q0.y, zv, acc[1]);
      acc[2]  = fmaf(q0.z, zv, acc[2]);
      acc[3]  = fmaf(q0.w, zv, acc[3]);
      acc[4]  = fmaf(q1.x, zv, acc[4]);
      acc[5]  = fmaf(q1.y, zv, acc[5]);
      acc[6]  = fmaf(q1.z, zv, acc[6]);
      acc[7]  = fmaf(q1.w, zv, acc[7]);
      acc[8]  = fmaf(q2.x, zv, acc[8]);
      acc[9]  = fmaf(q2.y, zv, acc[9]);
      acc[10] = fmaf(q2.z, zv, acc[10]);
      acc[11] = fmaf(q2.w, zv, acc[11]);
      acc[12] = fmaf(q3.x, zv, acc[12]);
      acc[13] = fmaf(q3.y, zv, acc[13]);
      acc[14] = fmaf(q3.z, zv, acc[14]);
      acc[15] = fmaf(q3.w, zv, acc[15]);
    }
    __syncthreads();   // next-tile buffer staged AND current buffer consumed
  }

  // reduce L over jb, then normalize
  Lred[jb][ha][ia] = Lp;
  __syncthreads();
  if (t < 64) {
    const int ia2 = t & 15, ha2 = t >> 4;
    const float L = Lred[0][ha2][ia2] + Lred[1][ha2][ia2] +
                    Lred[2][ha2][ia2] + Lred[3][ha2][ia2];
    rl_lds[ia2][ha2] = (L > 0.f) ? 1.0f / L : 0.f;  // fully-masked row -> 0 (matches ref)
  }
  __syncthreads();
  const long ob = ((long)(b * NN + i0)) * TOT + t;
#pragma unroll
  for (int i = 0; i < TI; ++i)
    out[ob + (long)i * TOT] = acc[i] * rl_lds[i][h];
}

extern "C" void kernel_launch(void* const* d_in, const int* in_sizes, int n_in,
                              void* d_out, int out_size, void* d_ws, size_t ws_size,
                              hipStream_t stream) {
  const float* nodes = (const float*)d_in[0];
  const int*   adjm  = (const int*)d_in[1];
  const float* Wp    = (const float*)d_in[2];
  const float* bp    = (const float*)d_in[3];
  const float* asrc  = (const float*)d_in[4];
  const float* atgt  = (const float*)d_in[5];
  float* srcO = (float*)d_ws;                  // 128 KB
  float* tgtO = srcO + NB * NN * NH;           // 128 KB
  float* proj = tgtO + NB * NN * NH;           // 8 MB
  float* out = (float*)d_out;                  // f32 output

  proj_kernel<<<NB * NN / 4, 256, 0, stream>>>(nodes, Wp, bp, proj);
  srctgt_kernel<<<NB * NN, 64, 0, stream>>>(proj, asrc, atgt, srcO, tgtO);
  agg_kernel<<<NB * (NN / TI), 256, 0, stream>>>(adjm, proj, srcO, tgtO, out);
}

// Round 14
// 522.096 us; speedup vs baseline: 1.0293x; 1.0293x over previous
//
#include <hip/hip_runtime.h>
#include <hip/hip_bf16.h>
#include <math.h>

#define NB 4
#define NN 2048
#define IND 256
#define TOT 256
#define NH 4
#define TI 16
#define TJ 32
#define M0V 4.0f   // fixed softmax shift; e = leaky(src+tgt) provably < 4

// ---------------- K1: proj = nodes @ W + b   (4 rows per block)
__global__ __launch_bounds__(256) void proj_kernel(
    const float* __restrict__ nodes, const float* __restrict__ Wp,
    const float* __restrict__ bp, float* __restrict__ proj) {
  __shared__ float nrow[4][IND];
  const int t = threadIdx.x;
  const int r0 = blockIdx.x * 4;
#pragma unroll
  for (int r = 0; r < 4; ++r) nrow[r][t] = nodes[(r0 + r) * IND + t];
  __syncthreads();
  float a0, a1, a2, a3;
  a0 = a1 = a2 = a3 = bp[t];
  for (int k = 0; k < IND; ++k) {
    const float w = Wp[k * TOT + t];
    a0 = fmaf(nrow[0][k], w, a0);
    a1 = fmaf(nrow[1][k], w, a1);
    a2 = fmaf(nrow[2][k], w, a2);
    a3 = fmaf(nrow[3][k], w, a3);
  }
  proj[(r0 + 0) * TOT + t] = a0;
  proj[(r0 + 1) * TOT + t] = a1;
  proj[(r0 + 2) * TOT + t] = a2;
  proj[(r0 + 3) * TOT + t] = a3;
}

// ---------------- K2: src/tgt = proj @ a_{src,tgt}   (1 wave per node, LDS tree)
__global__ __launch_bounds__(64) void srctgt_kernel(
    const float* __restrict__ proj, const float* __restrict__ asrc,
    const float* __restrict__ atgt, float* __restrict__ srcO,
    float* __restrict__ tgtO) {
  __shared__ float sred[64];
  const int t = threadIdx.x;
  const int n = blockIdx.x;
  float p[8] = {0.f, 0.f, 0.f, 0.f, 0.f, 0.f, 0.f, 0.f};
#pragma unroll
  for (int c = 0; c < 4; ++c) {
    const int col = t + 64 * c;
    const float v = proj[n * TOT + col];
    const float4 as = ((const float4*)asrc)[col];
    const float4 at = ((const float4*)atgt)[col];
    p[0] = fmaf(v, as.x, p[0]);
    p[1] = fmaf(v, as.y, p[1]);
    p[2] = fmaf(v, as.z, p[2]);
    p[3] = fmaf(v, as.w, p[3]);
    p[4] = fmaf(v, at.x, p[4]);
    p[5] = fmaf(v, at.y, p[5]);
    p[6] = fmaf(v, at.z, p[6]);
    p[7] = fmaf(v, at.w, p[7]);
  }
#pragma unroll
  for (int v = 0; v < 8; ++v) {
    sred[t] = p[v];
    __syncthreads();
    for (int s = 32; s > 0; s >>= 1) {
      if (t < s) sred[t] += sred[t + s];
      __syncthreads();
    }
    if (t == 0) {
      if (v < 4) srcO[n * NH + v] = sred[0];
      else       tgtO[n * NH + (v - 4)] = sred[0];
    }
    __syncthreads();
  }
}

#define ZLOAD(buf, c)                                                        \
  _Pragma("unroll")                                                          \
  for (int u = 0; u < 8; ++u)                                                \
    buf[u] = zB[(jt * TJ + (c) * 8 + u) * TOT + t];

#define ZPV(buf, c)                                                          \
  _Pragma("unroll")                                                          \
  for (int u = 0; u < 8; ++u) {                                              \
    const float4* __restrict__ ap =                                          \
        (const float4*)&alpha_lds[cur][((c) * 8 + u) * 64 + h * 16];         \
    const float4 q0 = ap[0], q1 = ap[1], q2 = ap[2], q3 = ap[3];             \
    const float zv = buf[u];                                                 \
    acc[0]  = fmaf(q0.x, zv, acc[0]);                                        \
    acc[1]  = fmaf(q0.y, zv, acc[1]);                                        \
    acc[2]  = fmaf(q0.z, zv, acc[2]);                                        \
    acc[3]  = fmaf(q0.w, zv, acc[3]);                                        \
    acc[4]  = fmaf(q1.x, zv, acc[4]);                                        \
    acc[5]  = fmaf(q1.y, zv, acc[5]);                                        \
    acc[6]  = fmaf(q1.z, zv, acc[6]);                                        \
    acc[7]  = fmaf(q1.w, zv, acc[7]);                                        \
    acc[8]  = fmaf(q2.x, zv, acc[8]);                                        \
    acc[9]  = fmaf(q2.y, zv, acc[9]);                                        \
    acc[10] = fmaf(q2.z, zv, acc[10]);                                       \
    acc[11] = fmaf(q2.w, zv, acc[11]);                                       \
    acc[12] = fmaf(q3.x, zv, acc[12]);                                       \
    acc[13] = fmaf(q3.y, zv, acc[13]);                                       \
    acc[14] = fmaf(q3.z, zv, acc[14]);                                       \
    acc[15] = fmaf(q3.w, zv, acc[15]);                                       \
  }

// ---------------- K3: fused unnormalized softmax-agg, 1 barrier per j-tile,
// 8-deep pipelined z prefetch (VGPR-bounded; R13's zr[32] spilled at 256 VGPR).
__global__ __launch_bounds__(256) void agg_kernel(
    const int* __restrict__ adj, const float* __restrict__ proj,
    const float* __restrict__ srcI, const float* __restrict__ tgtI,
    float* __restrict__ out) {
  __shared__ float4 tgt_lds[NN];             // 32 KB
  __shared__ unsigned int bm_lds[TI * 66];   // 4.2 KB
  __shared__ float alpha_lds[2][TJ * 64];    // 16 KB double buffer (unnormalized e)
  __shared__ float Lred[4][NH][TI];
  __shared__ float rl_lds[TI][NH];
  const int t = threadIdx.x;
  const int b = blockIdx.x >> 7;
  const int i0 = (blockIdx.x & 127) << 4;
  const int* __restrict__ adjB = adj + (b * NN + i0) * NN;

#pragma unroll
  for (int c = 0; c < 8; ++c) {
    const int j = t + 256 * c;
    tgt_lds[j] = ((const float4*)tgtI)[b * NN + j];
  }
  const int wv = t >> 6, lane = t & 63;
#pragma unroll
  for (int r8 = 0; r8 < 4; ++r8) {
    const int r = wv * 4 + r8;
    const int* __restrict__ arowS = adjB + r * NN;
#pragma unroll 4
    for (int c = 0; c < 32; ++c) {
      const unsigned long long m = __ballot(arowS[c * 64 + lane] > 0);
      if (lane == 0)
        *(unsigned long long*)&bm_lds[r * 66 + c * 2] = m;
    }
  }
  __syncthreads();

  const int ia = t & 15, ha = (t >> 4) & 3, jb = t >> 6;
  const int h = jb;                        // wave == head; t = h*64 + d
  const float svv = srcI[(b * NN + i0 + ia) * NH + ha];
  const float* __restrict__ zB = proj + (long)(b * NN) * TOT;
  float acc[TI];
#pragma unroll
  for (int i = 0; i < TI; ++i) acc[i] = 0.f;
  float Lp = 0.f;

  // prologue: stage jt=0 into buffer 0
  {
    const unsigned int word = bm_lds[ia * 66];
#pragma unroll
    for (int s = 0; s < 8; ++s) {
      const int jl = jb + s * 4;
      const float tv = ((const float*)&tgt_lds[jl])[ha];
      float e0 = svv + tv;
      e0 = e0 >= 0.f ? e0 : 0.2f * e0;
      const float v = ((word >> jl) & 1) ? __expf(e0 - M0V) : 0.f;
      alpha_lds[0][jl * 64 + ha * 16 + ia] = v;
      Lp += v;
    }
  }
  __syncthreads();

  for (int jt = 0; jt < NN / TJ; ++jt) {
    const int cur = jt & 1;
    float zrA[8], zrB[8];
    ZLOAD(zrA, 0)                          // chunk 0 in flight
    // stage next tile into other buffer (VALU work hides zrA latency)
    if (jt < NN / TJ - 1) {
      const unsigned int word = bm_lds[ia * 66 + jt + 1];
#pragma unroll
      for (int s = 0; s < 8; ++s) {
        const int jl = jb + s * 4;
        const int jj = (jt + 1) * TJ + jl;
        const float tv = ((const float*)&tgt_lds[jj])[ha];
        float e0 = svv + tv;
        e0 = e0 >= 0.f ? e0 : 0.2f * e0;
        const float v = ((word >> jl) & 1) ? __expf(e0 - M0V) : 0.f;
        alpha_lds[cur ^ 1][jl * 64 + ha * 16 + ia] = v;
        Lp += v;
      }
    }
    ZLOAD(zrB, 1)                          // chunk 1 in flight
    ZPV(zrA, 0)
    ZLOAD(zrA, 2)                          // chunk 2 in flight
    ZPV(zrB, 1)
    ZLOAD(zrB, 3)                          // chunk 3 in flight
    ZPV(zrA, 2)
    ZPV(zrB, 3)
    __syncthreads();   // next-tile buffer staged AND current buffer consumed
  }

  // reduce L over jb, then normalize
  Lred[jb][ha][ia] = Lp;
  __syncthreads();
  if (t < 64) {
    const int ia2 = t & 15, ha2 = t >> 4;
    const float L = Lred[0][ha2][ia2] + Lred[1][ha2][ia2] +
                    Lred[2][ha2][ia2] + Lred[3][ha2][ia2];
    rl_lds[ia2][ha2] = (L > 0.f) ? 1.0f / L : 0.f;  // fully-masked row -> 0 (matches ref)
  }
  __syncthreads();
  const long ob = ((long)(b * NN + i0)) * TOT + t;
#pragma unroll
  for (int i = 0; i < TI; ++i)
    out[ob + (long)i * TOT] = acc[i] * rl_lds[i][h];
}

extern "C" void kernel_launch(void* const* d_in, const int* in_sizes, int n_in,
                              void* d_out, int out_size, void* d_ws, size_t ws_size,
                              hipStream_t stream) {
  const float* nodes = (const float*)d_in[0];
  const int*   adjm  = (const int*)d_in[1];
  const float* Wp    = (const float*)d_in[2];
  const float* bp    = (const float*)d_in[3];
  const float* asrc  = (const float*)d_in[4];
  const float* atgt  = (const float*)d_in[5];
  float* srcO = (float*)d_ws;                  // 128 KB
  float* tgtO = srcO + NB * NN * NH;           // 128 KB
  float* proj = tgtO + NB * NN * NH;           // 8 MB
  float* out = (float*)d_out;                  // f32 output

  proj_kernel<<<NB * NN / 4, 256, 0, stream>>>(nodes, Wp, bp, proj);
  srctgt_kernel<<<NB * NN, 64, 0, stream>>>(proj, asrc, atgt, srcO, tgtO);
  agg_kernel<<<NB * (NN / TI), 256, 0, stream>>>(adjm, proj, srcO, tgtO, out);
}

// Round 17
// 382.522 us; speedup vs baseline: 1.4049x; 1.3649x over previous
//
#include <hip/hip_runtime.h>
#include <hip/hip_bf16.h>
#include <math.h>

#define NB 4
#define NN 2048
#define IND 256
#define TOT 256
#define NH 4
#define TI 8
#define TJ 32
#define M0V 4.0f   // fixed softmax shift; e = leaky(src+tgt) provably < 4

// ---------------- K1: proj = nodes @ W + b   (4 rows per block)
__global__ __launch_bounds__(256) void proj_kernel(
    const float* __restrict__ nodes, const float* __restrict__ Wp,
    const float* __restrict__ bp, float* __restrict__ proj) {
  __shared__ float nrow[4][IND];
  const int t = threadIdx.x;
  const int r0 = blockIdx.x * 4;
#pragma unroll
  for (int r = 0; r < 4; ++r) nrow[r][t] = nodes[(r0 + r) * IND + t];
  __syncthreads();
  float a0, a1, a2, a3;
  a0 = a1 = a2 = a3 = bp[t];
  for (int k = 0; k < IND; ++k) {
    const float w = Wp[k * TOT + t];
    a0 = fmaf(nrow[0][k], w, a0);
    a1 = fmaf(nrow[1][k], w, a1);
    a2 = fmaf(nrow[2][k], w, a2);
    a3 = fmaf(nrow[3][k], w, a3);
  }
  proj[(r0 + 0) * TOT + t] = a0;
  proj[(r0 + 1) * TOT + t] = a1;
  proj[(r0 + 2) * TOT + t] = a2;
  proj[(r0 + 3) * TOT + t] = a3;
}

// ---------------- K2: src/tgt = proj @ a_{src,tgt}   (1 wave per node, LDS tree)
__global__ __launch_bounds__(64) void srctgt_kernel(
    const float* __restrict__ proj, const float* __restrict__ asrc,
    const float* __restrict__ atgt, float* __restrict__ srcO,
    float* __restrict__ tgtO) {
  __shared__ float sred[64];
  const int t = threadIdx.x;
  const int n = blockIdx.x;
  float p[8] = {0.f, 0.f, 0.f, 0.f, 0.f, 0.f, 0.f, 0.f};
#pragma unroll
  for (int c = 0; c < 4; ++c) {
    const int col = t + 64 * c;
    const float v = proj[n * TOT + col];
    const float4 as = ((const float4*)asrc)[col];
    const float4 at = ((const float4*)atgt)[col];
    p[0] = fmaf(v, as.x, p[0]);
    p[1] = fmaf(v, as.y, p[1]);
    p[2] = fmaf(v, as.z, p[2]);
    p[3] = fmaf(v, as.w, p[3]);
    p[4] = fmaf(v, at.x, p[4]);
    p[5] = fmaf(v, at.y, p[5]);
    p[6] = fmaf(v, at.z, p[6]);
    p[7] = fmaf(v, at.w, p[7]);
  }
#pragma unroll
  for (int v = 0; v < 8; ++v) {
    sred[t] = p[v];
    __syncthreads();
    for (int s = 32; s > 0; s >>= 1) {
      if (t < s) sred[t] += sred[t + s];
      __syncthreads();
    }
    if (t == 0) {
      if (v < 4) srcO[n * NH + v] = sred[0];
      else       tgtO[n * NH + (v - 4)] = sred[0];
    }
    __syncthreads();
  }
}

// ---------------- K3: fused unnormalized softmax-agg.
// TI=8 (grid 1024 -> 3 blocks/CU), double-buffered alpha, 1 barrier/jt,
// direct z loads (R12-proven codegen), VGPR capped at 128 via launch_bounds.
// Thread decode: ia=t&7, ha=(t>>3)&3, jb=t>>5 (staging);  h=t>>6, d=t&63 (PV).
__global__ __launch_bounds__(256, 4) void agg_kernel(
    const int* __restrict__ adj, const float* __restrict__ proj,
    const float* __restrict__ srcI, const float* __restrict__ tgtI,
    float* __restrict__ out) {
  __shared__ float4 tgt_lds[NN];             // 32 KB
  __shared__ unsigned int bm_lds[TI * 66];   // 2.1 KB
  __shared__ float alpha_lds[2][TJ * 32];    // 8 KB double buffer: [jl][ha][ia]
  __shared__ float Lred[8][NH][TI];          // [jb][ha][ia] 1 KB
  __shared__ float rl_lds[TI][NH];
  const int t = threadIdx.x;
  const int b = blockIdx.x >> 8;             // 256 tiles per batch
  const int i0 = (blockIdx.x & 255) << 3;
  const int* __restrict__ adjB = adj + (b * NN + i0) * NN;

#pragma unroll
  for (int c = 0; c < 8; ++c) {
    const int j = t + 256 * c;
    tgt_lds[j] = ((const float4*)tgtI)[b * NN + j];
  }
  // stage adjacency bitmask: wave wv packs rows 2wv..2wv+1, coalesced + ballot
  const int wv = t >> 6, lane = t & 63;
#pragma unroll
  for (int r8 = 0; r8 < 2; ++r8) {
    const int r = wv * 2 + r8;
    const int* __restrict__ arowS = adjB + r * NN;
#pragma unroll 4
    for (int c = 0; c < 32; ++c) {
      const unsigned long long m = __ballot(arowS[c * 64 + lane] > 0);
      if (lane == 0)
        *(unsigned long long*)&bm_lds[r * 66 + c * 2] = m;
    }
  }
  __syncthreads();

  const int ia = t & 7, ha = (t >> 3) & 3, jb = t >> 5;
  const int h = t >> 6;                      // wave == head; t = h*64 + d
  const float svv = srcI[(b * NN + i0 + ia) * NH + ha];
  const float* __restrict__ zB = proj + (long)(b * NN) * TOT;
  float acc[TI];
#pragma unroll
  for (int i = 0; i < TI; ++i) acc[i] = 0.f;
  float Lp = 0.f;

  // prologue: stage jt=0 into buffer 0 (each thread: jl = jb + 8s, s<4)
  {
    const unsigned int word = bm_lds[ia * 66];
#pragma unroll
    for (int s = 0; s < 4; ++s) {
      const int jl = jb + s * 8;
      const float tv = ((const float*)&tgt_lds[jl])[ha];
      float e0 = svv + tv;
      e0 = e0 >= 0.f ? e0 : 0.2f * e0;
      const float v = ((word >> jl) & 1) ? __expf(e0 - M0V) : 0.f;
      alpha_lds[0][jl * 32 + ha * 8 + ia] = v;
      Lp += v;
    }
  }
  __syncthreads();

  for (int jt = 0; jt < NN / TJ; ++jt) {
    const int cur = jt & 1;
    // stage next tile into the other buffer
    if (jt < NN / TJ - 1) {
      const unsigned int word = bm_lds[ia * 66 + jt + 1];
#pragma unroll
      for (int s = 0; s < 4; ++s) {
        const int jl = jb + s * 8;
        const int jj = (jt + 1) * TJ + jl;
        const float tv = ((const float*)&tgt_lds[jj])[ha];
        float e0 = svv + tv;
        e0 = e0 >= 0.f ? e0 : 0.2f * e0;
        const float v = ((word >> jl) & 1) ? __expf(e0 - M0V) : 0.f;
        alpha_lds[cur ^ 1][jl * 32 + ha * 8 + ia] = v;
        Lp += v;
      }
    }
    // PV on current buffer: direct z loads (coalesced), broadcast LDS alpha
#pragma unroll 8
    for (int jl = 0; jl < TJ; ++jl) {
      const float zv = zB[(jt * TJ + jl) * TOT + t];
      const float4* __restrict__ ap = (const float4*)&alpha_lds[cur][jl * 32 + h * 8];
      const float4 q0 = ap[0], q1 = ap[1];
      acc[0] = fmaf(q0.x, zv, acc[0]);
      acc[1] = fmaf(q0.y, zv, acc[1]);
      acc[2] = fmaf(q0.z, zv, acc[2]);
      acc[3] = fmaf(q0.w, zv, acc[3]);
      acc[4] = fmaf(q1.x, zv, acc[4]);
      acc[5] = fmaf(q1.y, zv, acc[5]);
      acc[6] = fmaf(q1.z, zv, acc[6]);
      acc[7] = fmaf(q1.w, zv, acc[7]);
    }
    __syncthreads();   // next buffer staged AND current consumed
  }

  // reduce L over jb, then normalize
  Lred[jb][ha][ia] = Lp;
  __syncthreads();
  if (t < 32) {
    const int ia2 = t & 7, ha2 = t >> 3;
    float L = 0.f;
#pragma unroll
    for (int q = 0; q < 8; ++q) L += Lred[q][ha2][ia2];
    rl_lds[ia2][ha2] = (L > 0.f) ? 1.0f / L : 0.f;  // fully-masked row -> 0 (matches ref)
  }
  __syncthreads();
  const long ob = ((long)(b * NN + i0)) * TOT + t;
#pragma unroll
  for (int i = 0; i < TI; ++i)
    out[ob + (long)i * TOT] = acc[i] * rl_lds[i][h];
}

extern "C" void kernel_launch(void* const* d_in, const int* in_sizes, int n_in,
                              void* d_out, int out_size, void* d_ws, size_t ws_size,
                              hipStream_t stream) {
  const float* nodes = (const float*)d_in[0];
  const int*   adjm  = (const int*)d_in[1];
  const float* Wp    = (const float*)d_in[2];
  const float* bp    = (const float*)d_in[3];
  const float* asrc  = (const float*)d_in[4];
  const float* atgt  = (const float*)d_in[5];
  float* srcO = (float*)d_ws;                  // 128 KB
  float* tgtO = srcO + NB * NN * NH;           // 128 KB
  float* proj = tgtO + NB * NN * NH;           // 8 MB
  float* out = (float*)d_out;                  // f32 output

  proj_kernel<<<NB * NN / 4, 256, 0, stream>>>(nodes, Wp, bp, proj);
  srctgt_kernel<<<NB * NN, 64, 0, stream>>>(proj, asrc, atgt, srcO, tgtO);
  agg_kernel<<<NB * (NN / TI), 256, 0, stream>>>(adjm, proj, srcO, tgtO, out);
}